// Round 1
// baseline (494.632 us; speedup 1.0000x reference)
//
#include <hip/hip_runtime.h>
#include <stdint.h>

// GeometricBilinear (PGA 3,0,1) fused kernel.
// Layout: 256 thr/block = 8 positions x 32 roles (role<16: gp side channels,
// role>=16: join side). Block loops 4 tiles of 8 positions (CHUNK=32).
#define NPOS_TOTAL 32768
#define POS_PER_TILE 8
#define TILES_PER_BLOCK 4
#define CHUNK (POS_PER_TILE * TILES_PER_BLOCK)

// ---------------- constexpr PGA(3,0,1) blade tables ----------------
// BLADES order from reference; mask bit g <=> generator e_g present.
constexpr int BLADE_MASK[16] = {0,1,2,4,8,3,5,9,6,10,12,7,11,13,14,15};
constexpr int MASK2IDX[16]   = {0,1,2,5,3,6,8,11,4,7,9,12,10,13,14,15};

struct MulRes { int sign; int mask; };

constexpr MulRes mul_blades(int ma, int mb) {
  int lst[8] = {0,0,0,0,0,0,0,0};
  int n = 0;
  for (int g = 0; g < 4; ++g) if ((ma >> g) & 1) lst[n++] = g;
  for (int g = 0; g < 4; ++g) if ((mb >> g) & 1) lst[n++] = g;
  int sign = 1;
  bool changed = true;
  while (changed) {
    changed = false;
    int k = 0;
    while (k + 1 < n) {
      if (lst[k] > lst[k+1]) {
        int t = lst[k]; lst[k] = lst[k+1]; lst[k+1] = t;
        sign = -sign; changed = true;
      } else if (lst[k] == lst[k+1]) {
        if (lst[k] == 0) sign = 0;            // METRIC = [0,1,1,1]
        for (int m = k; m + 2 < n; ++m) lst[m] = lst[m+2];
        n -= 2; changed = true;
      } else {
        ++k;
      }
    }
  }
  int mask = 0;
  for (int m = 0; m < n; ++m) mask |= (1 << lst[m]);
  if (sign == 0) mask = 0;
  return MulRes{sign, mask};
}

struct Tables {
  float gp_sgn[16][16]; int gp_idx[16][16];
  float jn_sgn[16][16]; int jn_idx[16][16];
  constexpr Tables() : gp_sgn{}, gp_idx{}, jn_sgn{}, jn_idx{} {
    for (int j = 0; j < 16; ++j) {
      for (int k = 0; k < 16; ++k) {
        MulRes r = mul_blades(BLADE_MASK[j], BLADE_MASK[k]);
        gp_sgn[j][k] = (float)r.sign;
        gp_idx[j][k] = MASK2IDX[r.mask & 15];
        jn_sgn[j][k] = 0.0f; jn_idx[j][k] = 0;
        int mb = BLADE_MASK[j], mc = BLADE_MASK[k];
        if ((mb | mc) == 15) {                 // join nonzero iff duals disjoint
          int cb = 15 ^ mb, cc = 15 ^ mc;
          MulRes sb = mul_blades(mb, cb);      // D sign for column b
          MulRes sc = mul_blades(mc, cc);      // D sign for column c
          MulRes ro = mul_blades(cb, cc);      // outer of the duals
          int imask = ro.mask;
          int amask = 15 ^ imask;
          MulRes si = mul_blades(imask, amask);// D sign for column i
          jn_sgn[j][k] = (float)(si.sign * ro.sign * sb.sign * sc.sign);
          jn_idx[j][k] = MASK2IDX[amask & 15];
        }
      }
    }
  }
};
constexpr Tables TBL{};

// ---------------- bf16 helpers (pack pairs in u32) ----------------
__device__ __forceinline__ float bflo(unsigned u) { return __uint_as_float(u << 16); }
__device__ __forceinline__ float bfhi(unsigned u) { return __uint_as_float(u & 0xffff0000u); }
__device__ __forceinline__ unsigned packbf(float a, float b) {
  unsigned ua = __float_as_uint(a), ub = __float_as_uint(b);
  unsigned ra = (ua + 0x7fffu + ((ua >> 16) & 1u)) >> 16;   // RNE
  unsigned rb = (ub + 0x7fffu + ((ub >> 16) & 1u)) >> 16;
  return (ra & 0xffffu) | ((rb & 0xffffu) << 16);
}

// Sparse equivariant-linear accumulation: out[j] += sum of basis-mapped terms.
// w[0..4]: grade-projection weights, w[5..8]: e0-wedge weights.
__device__ __forceinline__ void equi_accum(float* acc, const float* w, const float* x) {
  acc[0]  += w[0]*x[0];
  acc[1]  += w[1]*x[1]  + w[5]*x[0];
  acc[2]  += w[1]*x[2];
  acc[3]  += w[1]*x[3];
  acc[4]  += w[1]*x[4];
  acc[5]  += w[2]*x[5]  + w[6]*x[2];
  acc[6]  += w[2]*x[6]  + w[6]*x[3];
  acc[7]  += w[2]*x[7]  + w[6]*x[4];
  acc[8]  += w[2]*x[8];
  acc[9]  += w[2]*x[9];
  acc[10] += w[2]*x[10];
  acc[11] += w[3]*x[11] + w[7]*x[8];
  acc[12] += w[3]*x[12] + w[7]*x[9];
  acc[13] += w[3]*x[13] + w[7]*x[10];
  acc[14] += w[3]*x[14];
  acc[15] += w[4]*x[15] + w[8]*x[14];
}

// ---------------- prep: pack stage-3 + scalar weights to bf16 pairs in ws ----
// ws u32 layout: [0,5120) w_out_mv [c][b2][o]; [5120,6144) s2mv [k2][o];
// [6144,7168) mvs2s [c2][o2]; [7168,9216) s2s [k2][o2]; [9216,11264) w1s [k2][ab][c32]
__global__ void gb_prep(const float* __restrict__ womv, const float* __restrict__ ws2mv,
                        const float* __restrict__ wm2s, const float* __restrict__ ws2s,
                        const float* __restrict__ wls,  const float* __restrict__ wrs,
                        const float* __restrict__ wjls, const float* __restrict__ wjrs,
                        unsigned int* __restrict__ wpk) {
  const float* wss[4] = {wls, wrs, wjls, wjrs};
  for (int e = blockIdx.x * 256 + threadIdx.x; e < 11264; e += gridDim.x * 256) {
    unsigned v;
    if (e < 5120) {                 // w_out_mv (32o,32c,9b) -> [c*160 + b2*32 + o]
      int o = e & 31, b2 = (e >> 5) % 5, c = e / 160;
      const float* w = womv + o * 288 + c * 9;
      float f0 = w[b2 * 2];
      float f1 = (b2 * 2 + 1 < 9) ? w[b2 * 2 + 1] : 0.0f;
      v = packbf(f0, f1);
    } else if (e < 6144) {          // w_out_s2mv (32o,64k) -> [k2*32 + o]
      int t = e - 5120; int o = t & 31, k2 = t >> 5;
      v = packbf(ws2mv[o * 64 + 2 * k2], ws2mv[o * 64 + 2 * k2 + 1]);
    } else if (e < 7168) {          // w_out_mvs2s (64o2,32c) -> [c2*64 + o2]
      int t = e - 6144; int o2 = t & 63, c2 = t >> 6;
      v = packbf(wm2s[o2 * 32 + 2 * c2], wm2s[o2 * 32 + 2 * c2 + 1]);
    } else if (e < 9216) {          // w_out_s2s (64o2,64k) -> [k2*64 + o2]
      int t = e - 7168; int o2 = t & 63, k2 = t >> 6;
      v = packbf(ws2s[o2 * 64 + 2 * k2], ws2s[o2 * 64 + 2 * k2 + 1]);
    } else {                        // stage-1 scalar weights -> [k2*64 + ab*32 + c32]
      int t = e - 9216; int c32 = t & 31, ab = (t >> 5) & 1, k2 = t >> 6;
      int set = (c32 >> 4) * 2 + ab, o = c32 & 15;
      const float* w = wss[set] + o * 64 + k2 * 2;
      v = packbf(w[0], w[1]);
    }
    wpk[e] = v;
  }
}

// ---------------- main fused kernel ----------------
__global__ __launch_bounds__(256) void gb_main(
    const float* __restrict__ mv, const float* __restrict__ ref,
    const float* __restrict__ s,
    const float* __restrict__ wlmv, const float* __restrict__ wrmv,
    const float* __restrict__ wjlmv, const float* __restrict__ wjrmv,
    const unsigned int* __restrict__ wpk,
    float* __restrict__ out_mv, float* __restrict__ out_s) {
  // LDS: stage-1 mv weights bf16 pairs [i][slot 0..9][c32] (40 KB) + hidden (8.3 KB)
  __shared__ unsigned int w1pk[10240];
  __shared__ unsigned int hlds[2080];   // [pos8]*260 + [c]*8 + q  (bank-padded)

  const int tid  = threadIdx.x;
  const int side = tid >> 7;            // 0: gp(left,right)  1: join(jl,jr)
  const int pos8 = (tid >> 4) & 7;
  const int r    = tid & 15;
  const int t32  = (side << 4) | r;     // hidden channel / out_mv row / weight column

  // ---- stage 0: stage-1 mv weights -> LDS (bf16 pairs) ----
  {
    const float* wmvs[4] = {wlmv, wrmv, wjlmv, wjrmv};
    for (int e = tid; e < 10240; e += 256) {
      int c32 = e & 31, slot = (e >> 5) % 10, i = e / 320;
      int set = (c32 >> 4) * 2 + (slot >= 5 ? 1 : 0);
      int o = c32 & 15, b0 = (slot % 5) * 2;
      const float* w = wmvs[set] + o * 288 + i * 9;
      float f0 = w[b0];
      float f1 = (b0 + 1 < 9) ? w[b0 + 1] : 0.0f;
      w1pk[e] = packbf(f0, f1);
    }
  }
  __syncthreads();

  const unsigned int* wop   = wpk;            // [c*160 + b2*32 + o]
  const unsigned int* s2mv  = wpk + 5120;     // [k2*32 + o]
  const unsigned int* m2s   = wpk + 6144;     // [c2*64 + o2]
  const unsigned int* s2sW  = wpk + 7168;     // [k2*64 + o2]
  const unsigned int* w1s   = wpk + 9216;     // [k2*64 + ab*32 + c32]

  const int posg_base = blockIdx.x * CHUNK;

  for (int tile = 0; tile < TILES_PER_BLOCK; ++tile) {
    const int pos_g = posg_base + tile * POS_PER_TILE + pos8;

    // ---- stage 1: two equivariant linears (A,B) for this channel ----
    float accA[16], accB[16];
    #pragma unroll
    for (int q = 0; q < 16; ++q) { accA[q] = 0.0f; accB[q] = 0.0f; }

    const float4* xp = (const float4*)(mv + (size_t)pos_g * 512);
    #pragma unroll 4
    for (int i = 0; i < 32; ++i) {
      float4 xa = xp[i*4+0], xb = xp[i*4+1], xc = xp[i*4+2], xd = xp[i*4+3];
      float x[16] = {xa.x,xa.y,xa.z,xa.w, xb.x,xb.y,xb.z,xb.w,
                     xc.x,xc.y,xc.z,xc.w, xd.x,xd.y,xd.z,xd.w};
      const unsigned int* wp = &w1pk[i * 320 + t32];
      float wa[10], wb[10];
      #pragma unroll
      for (int sl = 0; sl < 5; ++sl) {
        unsigned ua = wp[sl * 32];
        unsigned ub = wp[(5 + sl) * 32];
        wa[2*sl] = bflo(ua); wa[2*sl+1] = bfhi(ua);
        wb[2*sl] = bflo(ub); wb[2*sl+1] = bfhi(ub);
      }
      equi_accum(accA, wa, x);
      equi_accum(accB, wb, x);
    }
    // scalar contribution to component 0
    const float4* sp = (const float4*)(s + (size_t)pos_g * 64);
    #pragma unroll 4
    for (int q = 0; q < 16; ++q) {
      float4 sv = sp[q];
      unsigned a0 = w1s[(4*q+0)*32 + t32];
      unsigned b0 = w1s[(4*q+1)*32 + t32];
      unsigned a1 = w1s[(4*q+2)*32 + t32];
      unsigned b1 = w1s[(4*q+3)*32 + t32];
      accA[0] += bflo(a0)*sv.x + bfhi(a0)*sv.y + bflo(a1)*sv.z + bfhi(a1)*sv.w;
      accB[0] += bflo(b0)*sv.x + bfhi(b0)*sv.y + bflo(b1)*sv.z + bfhi(b1)*sv.w;
    }

    // ---- stage 2: channel-local bilinear (gp or join) ----
    float h[16];
    #pragma unroll
    for (int q = 0; q < 16; ++q) h[q] = 0.0f;
    if (side == 0) {
      #pragma unroll
      for (int j = 0; j < 16; ++j)
        #pragma unroll
        for (int k = 0; k < 16; ++k)
          if (TBL.gp_sgn[j][k] != 0.0f)
            h[TBL.gp_idx[j][k]] += TBL.gp_sgn[j][k] * accA[j] * accB[k];
    } else {
      #pragma unroll
      for (int j = 0; j < 16; ++j)
        #pragma unroll
        for (int k = 0; k < 16; ++k)
          if (TBL.jn_sgn[j][k] != 0.0f)
            h[TBL.jn_idx[j][k]] += TBL.jn_sgn[j][k] * accA[j] * accB[k];
      float rs = ref[(size_t)pos_g * 16 + 15];
      #pragma unroll
      for (int q = 0; q < 16; ++q) h[q] *= rs;
    }
    // pack hidden channel to LDS (bf16 pairs)
    {
      unsigned hp[8];
      #pragma unroll
      for (int q = 0; q < 8; ++q) hp[q] = packbf(h[2*q], h[2*q+1]);
      unsigned int* hb = &hlds[pos8 * 260 + t32 * 8];
      ((uint4*)hb)[0] = make_uint4(hp[0], hp[1], hp[2], hp[3]);
      ((uint4*)hb)[1] = make_uint4(hp[4], hp[5], hp[6], hp[7]);
    }
    __syncthreads();

    // ---- stage 3: output equivariant linear (this thread: o = t32) ----
    float acc[16];
    #pragma unroll
    for (int q = 0; q < 16; ++q) acc[q] = 0.0f;
    #pragma unroll 4
    for (int c = 0; c < 32; ++c) {
      const unsigned int* hq = &hlds[pos8 * 260 + c * 8];
      uint4 h0 = ((const uint4*)hq)[0];
      uint4 h1 = ((const uint4*)hq)[1];
      float hh[16] = {bflo(h0.x),bfhi(h0.x),bflo(h0.y),bfhi(h0.y),
                      bflo(h0.z),bfhi(h0.z),bflo(h0.w),bfhi(h0.w),
                      bflo(h1.x),bfhi(h1.x),bflo(h1.y),bfhi(h1.y),
                      bflo(h1.z),bfhi(h1.z),bflo(h1.w),bfhi(h1.w)};
      float w[10];
      #pragma unroll
      for (int b2 = 0; b2 < 5; ++b2) {
        unsigned u = wop[c * 160 + b2 * 32 + t32];
        w[2*b2] = bflo(u); w[2*b2+1] = bfhi(u);
      }
      equi_accum(acc, w, hh);
    }
    #pragma unroll 4
    for (int q = 0; q < 16; ++q) {
      float4 sv = sp[q];
      unsigned u0 = s2mv[(2*q)*32 + t32];
      unsigned u1 = s2mv[(2*q+1)*32 + t32];
      acc[0] += bflo(u0)*sv.x + bfhi(u0)*sv.y + bflo(u1)*sv.z + bfhi(u1)*sv.w;
    }
    {
      float4* op = (float4*)(out_mv + (size_t)pos_g * 512 + t32 * 16);
      op[0] = make_float4(acc[0],  acc[1],  acc[2],  acc[3]);
      op[1] = make_float4(acc[4],  acc[5],  acc[6],  acc[7]);
      op[2] = make_float4(acc[8],  acc[9],  acc[10], acc[11]);
      op[3] = make_float4(acc[12], acc[13], acc[14], acc[15]);
    }

    // ---- stage 4: scalar outputs (o2 = t32 and t32+32) ----
    float a0 = 0.0f, a1 = 0.0f;
    #pragma unroll
    for (int c2 = 0; c2 < 16; ++c2) {
      float hA = bflo(hlds[pos8 * 260 + (2*c2) * 8]);     // hidden[2c2][0]
      float hB = bflo(hlds[pos8 * 260 + (2*c2+1) * 8]);   // hidden[2c2+1][0]
      unsigned ua = m2s[c2 * 64 + t32];
      unsigned ub = m2s[c2 * 64 + t32 + 32];
      a0 += bflo(ua)*hA + bfhi(ua)*hB;
      a1 += bflo(ub)*hA + bfhi(ub)*hB;
    }
    #pragma unroll 4
    for (int q = 0; q < 16; ++q) {
      float4 sv = sp[q];
      unsigned ua0 = s2sW[(2*q)*64 + t32];
      unsigned ua1 = s2sW[(2*q+1)*64 + t32];
      unsigned ub0 = s2sW[(2*q)*64 + t32 + 32];
      unsigned ub1 = s2sW[(2*q+1)*64 + t32 + 32];
      a0 += bflo(ua0)*sv.x + bfhi(ua0)*sv.y + bflo(ua1)*sv.z + bfhi(ua1)*sv.w;
      a1 += bflo(ub0)*sv.x + bfhi(ub0)*sv.y + bflo(ub1)*sv.z + bfhi(ub1)*sv.w;
    }
    out_s[(size_t)pos_g * 64 + t32]      = a0;
    out_s[(size_t)pos_g * 64 + t32 + 32] = a1;

    __syncthreads();   // hlds reused next tile
  }
}

extern "C" void kernel_launch(void* const* d_in, const int* in_sizes, int n_in,
                              void* d_out, int out_size, void* d_ws, size_t ws_size,
                              hipStream_t stream) {
  (void)in_sizes; (void)n_in; (void)out_size; (void)ws_size;
  const float* mv    = (const float*)d_in[0];
  const float* ref   = (const float*)d_in[1];
  const float* s     = (const float*)d_in[2];
  // d_in[3..5] = basis/gp/jn tables: baked at compile time, unused.
  const float* wlmv  = (const float*)d_in[6];
  const float* wls   = (const float*)d_in[7];
  const float* wrmv  = (const float*)d_in[8];
  const float* wrs   = (const float*)d_in[9];
  const float* wjlmv = (const float*)d_in[10];
  const float* wjls  = (const float*)d_in[11];
  const float* wjrmv = (const float*)d_in[12];
  const float* wjrs  = (const float*)d_in[13];
  const float* womv  = (const float*)d_in[14];
  const float* ws2mv = (const float*)d_in[15];
  const float* wm2s  = (const float*)d_in[16];
  const float* ws2s  = (const float*)d_in[17];

  float* out_mv = (float*)d_out;
  float* out_s  = out_mv + (size_t)NPOS_TOTAL * 32 * 16;
  unsigned int* wpk = (unsigned int*)d_ws;

  gb_prep<<<11, 256, 0, stream>>>(womv, ws2mv, wm2s, ws2s, wls, wrs, wjls, wjrs, wpk);
  gb_main<<<NPOS_TOTAL / CHUNK, 256, 0, stream>>>(mv, ref, s, wlmv, wrmv, wjlmv, wjrmv,
                                                  wpk, out_mv, out_s);
}

// Round 3
// 191.935 us; speedup vs baseline: 2.5771x; 2.5771x over previous
//
#include <hip/hip_runtime.h>
#include <stdint.h>

// GeometricBilinear (PGA 3,0,1) — MFMA formulation.
// Per block: 16 positions, 256 threads (4 waves).
// stage1: 4 equi-linears as per-component GEMMs (M=64 stacked L/R/JL/JR, K=32, N=16 pos)
// stage2: channel-local gp/join bilinear on VALU
// stage3: output equi-linear (M=32, K=32 hidden ch) + scalar head (M=64) on MFMA.

#define NPOS_TOTAL 32768

typedef __attribute__((ext_vector_type(8))) short short8;
typedef __attribute__((ext_vector_type(4))) float f32x4;
#define MFMA16(a,b,c) __builtin_amdgcn_mfma_f32_16x16x32_bf16((a),(b),(c),0,0,0)

// ---------------- constexpr PGA(3,0,1) blade tables (verified R1) ----------------
constexpr int BLADE_MASK[16] = {0,1,2,4,8,3,5,9,6,10,12,7,11,13,14,15};
constexpr int MASK2IDX[16]   = {0,1,2,5,3,6,8,11,4,7,9,12,10,13,14,15};

struct MulRes { int sign; int mask; };

constexpr MulRes mul_blades(int ma, int mb) {
  int lst[8] = {0,0,0,0,0,0,0,0};
  int n = 0;
  for (int g = 0; g < 4; ++g) if ((ma >> g) & 1) lst[n++] = g;
  for (int g = 0; g < 4; ++g) if ((mb >> g) & 1) lst[n++] = g;
  int sign = 1;
  bool changed = true;
  while (changed) {
    changed = false;
    int k = 0;
    while (k + 1 < n) {
      if (lst[k] > lst[k+1]) {
        int t = lst[k]; lst[k] = lst[k+1]; lst[k+1] = t;
        sign = -sign; changed = true;
      } else if (lst[k] == lst[k+1]) {
        if (lst[k] == 0) sign = 0;            // METRIC = [0,1,1,1]
        for (int m = k; m + 2 < n; ++m) lst[m] = lst[m+2];
        n -= 2; changed = true;
      } else {
        ++k;
      }
    }
  }
  int mask = 0;
  for (int m = 0; m < n; ++m) mask |= (1 << lst[m]);
  if (sign == 0) mask = 0;
  return MulRes{sign, mask};
}

struct Tables {
  float gp_sgn[16][16]; int gp_idx[16][16];
  float jn_sgn[16][16]; int jn_idx[16][16];
  constexpr Tables() : gp_sgn{}, gp_idx{}, jn_sgn{}, jn_idx{} {
    for (int j = 0; j < 16; ++j) {
      for (int k = 0; k < 16; ++k) {
        MulRes r = mul_blades(BLADE_MASK[j], BLADE_MASK[k]);
        gp_sgn[j][k] = (float)r.sign;
        gp_idx[j][k] = MASK2IDX[r.mask & 15];
        jn_sgn[j][k] = 0.0f; jn_idx[j][k] = 0;
        int mb = BLADE_MASK[j], mc = BLADE_MASK[k];
        if ((mb | mc) == 15) {
          int cb = 15 ^ mb, cc = 15 ^ mc;
          MulRes sb = mul_blades(mb, cb);
          MulRes sc = mul_blades(mc, cc);
          MulRes ro = mul_blades(cb, cc);
          int imask = ro.mask;
          int amask = 15 ^ imask;
          MulRes si = mul_blades(imask, amask);
          jn_sgn[j][k] = (float)(si.sign * ro.sign * sb.sign * sc.sign);
          jn_idx[j][k] = MASK2IDX[amask & 15];
        }
      }
    }
  }
};
constexpr Tables TBL{};

// grade of each blade, and the e0-wedge (tgt <- src, w-slot) mapping
constexpr int GRADE[16] = {0,1,1,1,1,2,2,2,2,2,2,3,3,3,3,4};
constexpr int E0_TGT[8]  = {1,5,6,7,11,12,13,15};
constexpr int E0_SRC[8]  = {0,2,3,4,8,9,10,14};
constexpr int E0_SLOT[8] = {5,6,6,6,7,7,7,8};

// ---------------- helpers (manual RNE bf16 pack — R1-verified) ----------------
__device__ __forceinline__ float bflo(unsigned u) { return __uint_as_float(u << 16); }
__device__ __forceinline__ float bfhi(unsigned u) { return __uint_as_float(u & 0xffff0000u); }
__device__ __forceinline__ unsigned pk2(float a, float b) {
  unsigned ua = __float_as_uint(a), ub = __float_as_uint(b);
  unsigned ra = (ua + 0x7fffu + ((ua >> 16) & 1u)) >> 16;   // RNE
  unsigned rb = (ub + 0x7fffu + ((ub >> 16) & 1u)) >> 16;
  return (ra & 0xffffu) | ((rb & 0xffffu) << 16);
}
__device__ __forceinline__ unsigned short bf1(float a) {
  unsigned ua = __float_as_uint(a);
  return (unsigned short)((ua + 0x7fffu + ((ua >> 16) & 1u)) >> 16);
}

// ---------------- prep: pack all A-fragments (bf16) into ws ----------------
// 168 fragment blocks of 64 lanes x uint4 (8 bf16 in K order):
//  [0,104)  stage1: blk = mat*4 + ot   (mats: 16 grade, 8 e0, 2 scalar-half; ot 0..3, o=ot*16+m)
//  [104,156) stage3: blk = 104 + mat*2 + ot  (same mat order; ot 0..1, M=32)
//  [156,168) stage4: 156+ot: wm2s (64x32); 160+ot: ws2s half0; 164+ot: ws2s half1
__global__ void gb_prep(const float* __restrict__ wlmv, const float* __restrict__ wrmv,
                        const float* __restrict__ wjlmv, const float* __restrict__ wjrmv,
                        const float* __restrict__ wls,  const float* __restrict__ wrs,
                        const float* __restrict__ wjls, const float* __restrict__ wjrs,
                        const float* __restrict__ womv, const float* __restrict__ ws2mv,
                        const float* __restrict__ wm2s, const float* __restrict__ ws2s,
                        uint4* __restrict__ wpk) {
  int t = blockIdx.x * 256 + threadIdx.x;
  if (t >= 168 * 64) return;
  int blk = t >> 6, l = t & 63;
  int m = l & 15, q = l >> 4;
  float v[8];
  if (blk < 104) {
    int mat = blk >> 2, ot = blk & 3;
    const float* wmv[4] = {wlmv, wrmv, wjlmv, wjrmv};
    const float* wsc[4] = {wls, wrs, wjls, wjrs};
    for (int jj = 0; jj < 8; ++jj) {
      int k = q * 8 + jj;
      if (mat < 16)      v[jj] = wmv[ot][m * 288 + k * 9 + GRADE[mat]];
      else if (mat < 24) v[jj] = wmv[ot][m * 288 + k * 9 + E0_SLOT[mat - 16]];
      else               v[jj] = wsc[ot][m * 64 + (mat - 24) * 32 + k];
    }
  } else if (blk < 156) {
    int b2 = blk - 104, mat = b2 >> 1, ot = b2 & 1;
    int o = ot * 16 + m;
    for (int jj = 0; jj < 8; ++jj) {
      int k = q * 8 + jj;
      if (mat < 16)      v[jj] = womv[o * 288 + k * 9 + GRADE[mat]];
      else if (mat < 24) v[jj] = womv[o * 288 + k * 9 + E0_SLOT[mat - 16]];
      else               v[jj] = ws2mv[o * 64 + (mat - 24) * 32 + k];
    }
  } else {
    int b4 = blk - 156;
    for (int jj = 0; jj < 8; ++jj) {
      int k = q * 8 + jj;
      if (b4 < 4) { int o = b4 * 16 + m; v[jj] = wm2s[o * 32 + k]; }
      else { int half = (b4 - 4) >> 2, ot = (b4 - 4) & 3; int o = ot * 16 + m;
             v[jj] = ws2s[o * 64 + half * 32 + k]; }
    }
  }
  uint4 u;
  u.x = pk2(v[0], v[1]); u.y = pk2(v[2], v[3]);
  u.z = pk2(v[4], v[5]); u.w = pk2(v[6], v[7]);
  wpk[t] = u;
}

// ---------------- main fused kernel ----------------
__global__ __launch_bounds__(256) void gb_main(
    const float* __restrict__ mv, const float* __restrict__ ref,
    const float* __restrict__ s, const uint4* __restrict__ wpk,
    float* __restrict__ out_mv, float* __restrict__ out_s) {
  // region A [0,16640): xs [pos][comp][i] bf16 (pos stride 520 elems) -> later hlds [pos][comp][ch] (stride 520)
  // region B [16640,57600): ylds [o64][pos*20 + j] bf16 (40960 B)
  __shared__ __align__(16) char smem[57600];
  unsigned short* xs_e = (unsigned short*)smem;
  unsigned*       xs_w = (unsigned*)smem;
  unsigned short* hl_e = (unsigned short*)smem;
  unsigned short* yl_e = (unsigned short*)(smem + 16640);
  unsigned*       yl_w = (unsigned*)(smem + 16640);

  const int tid  = threadIdx.x;
  const int wave = tid >> 6, lane = tid & 63;
  const int lm = lane & 15, lq = lane >> 4;
  const int P0 = blockIdx.x * 16;

  // ---- stage 0: transpose mv tile into xs (bf16) ----
  const float4* mv4 = (const float4*)mv + (size_t)P0 * 128;
  #pragma unroll
  for (int kk = 0; kk < 4; ++kk) {
    int e = tid + kk * 256;              // 0..1023 tasks
    int p = e >> 6, sub = e & 63, i2 = sub >> 2, jg = sub & 3;
    float4 fa = mv4[p * 128 + i2 * 8 + jg];
    float4 fb = mv4[p * 128 + i2 * 8 + 4 + jg];
    int base = p * 260 + jg * 4 * 16 + i2;     // u32 index: [p][c][i-pair]
    xs_w[base + 0 * 16] = pk2(fa.x, fb.x);
    xs_w[base + 1 * 16] = pk2(fa.y, fb.y);
    xs_w[base + 2 * 16] = pk2(fa.z, fb.z);
    xs_w[base + 3 * 16] = pk2(fa.w, fb.w);
  }

  // ---- s B-fragments (K=64 -> 2 frags), per lane: pos=lm, k=half*32+lq*8+jj ----
  short8 sfrag[2];
  {
    const float4* s4 = (const float4*)s + ((size_t)(P0 + lm)) * 16;
    #pragma unroll
    for (int h = 0; h < 2; ++h) {
      float4 a = s4[h * 8 + lq * 2];
      float4 b = s4[h * 8 + lq * 2 + 1];
      uint4 u;
      u.x = pk2(a.x, a.y); u.y = pk2(a.z, a.w);
      u.z = pk2(b.x, b.y); u.w = pk2(b.z, b.w);
      sfrag[h] = __builtin_bit_cast(short8, u);
    }
  }
  __syncthreads();

  // ---- stage 1: 64-row stacked equi-linear via MFMA (this wave: o-tile = wave) ----
  {
    short8 bx[16];
    #pragma unroll
    for (int c = 0; c < 16; ++c)
      bx[c] = *(const short8*)&xs_e[lm * 520 + c * 32 + lq * 8];
    f32x4 zf = {0.f, 0.f, 0.f, 0.f};
    f32x4 acc[16];
    #pragma unroll
    for (int j = 0; j < 16; ++j) acc[j] = zf;
    #pragma unroll
    for (int j = 0; j < 16; ++j) {
      short8 w = __builtin_bit_cast(short8, wpk[(j * 4 + wave) * 64 + lane]);
      acc[j] = MFMA16(w, bx[j], acc[j]);
    }
    #pragma unroll
    for (int m = 0; m < 8; ++m) {
      short8 w = __builtin_bit_cast(short8, wpk[((16 + m) * 4 + wave) * 64 + lane]);
      acc[E0_TGT[m]] = MFMA16(w, bx[E0_SRC[m]], acc[E0_TGT[m]]);
    }
    #pragma unroll
    for (int h = 0; h < 2; ++h) {
      short8 w = __builtin_bit_cast(short8, wpk[((24 + h) * 4 + wave) * 64 + lane]);
      acc[0] = MFMA16(w, sfrag[h], acc[0]);
    }
    // D-frag: lane holds out[o = wave*16 + lq*4 + r][pos = lm]; pack j-pairs -> ylds
    #pragma unroll
    for (int jp = 0; jp < 8; ++jp) {
      #pragma unroll
      for (int r = 0; r < 4; ++r) {
        int o = wave * 16 + lq * 4 + r;
        yl_w[o * 160 + lm * 10 + jp] = pk2(acc[2 * jp][r], acc[2 * jp + 1][r]);
      }
    }
  }
  __syncthreads();

  // ---- stage 2: channel-local bilinear (VALU). thread t: pos=t&15, hc=t>>4 ----
  {
    const int pos = tid & 15;
    const int hc  = tid >> 4;
    const float rs = ref[(size_t)(P0 + pos) * 16 + 15];
    float L[16], R[16], H[16];
    auto ldrow = [&](int row, float* dst) {
      const unsigned short* p = yl_e + row * 320 + pos * 20;
      uint2 a = *(const uint2*)(p);
      uint2 b = *(const uint2*)(p + 4);
      uint2 c = *(const uint2*)(p + 8);
      uint2 d = *(const uint2*)(p + 12);
      unsigned uu[8] = {a.x, a.y, b.x, b.y, c.x, c.y, d.x, d.y};
      #pragma unroll
      for (int q = 0; q < 8; ++q) { dst[2*q] = bflo(uu[q]); dst[2*q+1] = bfhi(uu[q]); }
    };
    // gp pair -> hidden channel hc
    ldrow(hc, L); ldrow(16 + hc, R);
    #pragma unroll
    for (int q = 0; q < 16; ++q) H[q] = 0.f;
    #pragma unroll
    for (int j = 0; j < 16; ++j)
      #pragma unroll
      for (int k = 0; k < 16; ++k)
        if (TBL.gp_sgn[j][k] != 0.0f)
          H[TBL.gp_idx[j][k]] += TBL.gp_sgn[j][k] * L[j] * R[k];
    #pragma unroll
    for (int j = 0; j < 16; ++j)
      hl_e[pos * 520 + j * 32 + hc] = bf1(H[j]);
    // join pair -> hidden channel 16+hc (fold ref scale into L)
    ldrow(32 + hc, L); ldrow(48 + hc, R);
    #pragma unroll
    for (int q = 0; q < 16; ++q) { H[q] = 0.f; L[q] *= rs; }
    #pragma unroll
    for (int j = 0; j < 16; ++j)
      #pragma unroll
      for (int k = 0; k < 16; ++k)
        if (TBL.jn_sgn[j][k] != 0.0f)
          H[TBL.jn_idx[j][k]] += TBL.jn_sgn[j][k] * L[j] * R[k];
    #pragma unroll
    for (int j = 0; j < 16; ++j)
      hl_e[pos * 520 + j * 32 + 16 + hc] = bf1(H[j]);
  }
  __syncthreads();

  // ---- stage 3 (waves 0,1): output equi-linear. stage 4 (waves 2,3): scalar head ----
  if (wave < 2) {
    short8 bh[16];
    #pragma unroll
    for (int j = 0; j < 16; ++j)
      bh[j] = *(const short8*)&hl_e[lm * 520 + j * 32 + lq * 8];
    f32x4 zf = {0.f, 0.f, 0.f, 0.f};
    f32x4 a3[16];
    #pragma unroll
    for (int j = 0; j < 16; ++j) a3[j] = zf;
    #pragma unroll
    for (int j = 0; j < 16; ++j) {
      short8 w = __builtin_bit_cast(short8, wpk[(104 + j * 2 + wave) * 64 + lane]);
      a3[j] = MFMA16(w, bh[j], a3[j]);
    }
    #pragma unroll
    for (int m = 0; m < 8; ++m) {
      short8 w = __builtin_bit_cast(short8, wpk[(104 + (16 + m) * 2 + wave) * 64 + lane]);
      a3[E0_TGT[m]] = MFMA16(w, bh[E0_SRC[m]], a3[E0_TGT[m]]);
    }
    #pragma unroll
    for (int h = 0; h < 2; ++h) {
      short8 w = __builtin_bit_cast(short8, wpk[(104 + (24 + h) * 2 + wave) * 64 + lane]);
      a3[0] = MFMA16(w, sfrag[h], a3[0]);
    }
    // store: out_mv[pos][o][j], o = wave*16 + lq*4 + r, pos = lm; vectorize over j
    float* ob = out_mv + ((size_t)(P0 + lm)) * 512 + (size_t)(wave * 16 + lq * 4) * 16;
    #pragma unroll
    for (int r = 0; r < 4; ++r) {
      #pragma unroll
      for (int g = 0; g < 4; ++g) {
        *(float4*)(ob + r * 16 + g * 4) =
            make_float4(a3[4*g][r], a3[4*g+1][r], a3[4*g+2][r], a3[4*g+3][r]);
      }
    }
  } else {
    short8 bh0 = *(const short8*)&hl_e[lm * 520 + lq * 8];
    int w2 = wave - 2;
    f32x4 zf = {0.f, 0.f, 0.f, 0.f};
    #pragma unroll
    for (int t2 = 0; t2 < 2; ++t2) {
      int otg = w2 * 2 + t2;
      f32x4 aS = zf;
      aS = MFMA16(__builtin_bit_cast(short8, wpk[(156 + otg) * 64 + lane]), bh0, aS);
      aS = MFMA16(__builtin_bit_cast(short8, wpk[(160 + otg) * 64 + lane]), sfrag[0], aS);
      aS = MFMA16(__builtin_bit_cast(short8, wpk[(164 + otg) * 64 + lane]), sfrag[1], aS);
      float* osb = out_s + ((size_t)(P0 + lm)) * 64 + otg * 16 + lq * 4;
      *(float4*)osb = make_float4(aS[0], aS[1], aS[2], aS[3]);
    }
  }
}

extern "C" void kernel_launch(void* const* d_in, const int* in_sizes, int n_in,
                              void* d_out, int out_size, void* d_ws, size_t ws_size,
                              hipStream_t stream) {
  (void)in_sizes; (void)n_in; (void)out_size; (void)ws_size;
  const float* mv    = (const float*)d_in[0];
  const float* ref   = (const float*)d_in[1];
  const float* s     = (const float*)d_in[2];
  // d_in[3..5] = basis/gp/jn tables: baked at compile time.
  const float* wlmv  = (const float*)d_in[6];
  const float* wls   = (const float*)d_in[7];
  const float* wrmv  = (const float*)d_in[8];
  const float* wrs   = (const float*)d_in[9];
  const float* wjlmv = (const float*)d_in[10];
  const float* wjls  = (const float*)d_in[11];
  const float* wjrmv = (const float*)d_in[12];
  const float* wjrs  = (const float*)d_in[13];
  const float* womv  = (const float*)d_in[14];
  const float* ws2mv = (const float*)d_in[15];
  const float* wm2s  = (const float*)d_in[16];
  const float* ws2s  = (const float*)d_in[17];

  float* out_mv = (float*)d_out;
  float* out_s  = out_mv + (size_t)NPOS_TOTAL * 32 * 16;
  uint4* wpk = (uint4*)d_ws;

  gb_prep<<<42, 256, 0, stream>>>(wlmv, wrmv, wjlmv, wjrmv, wls, wrs, wjls, wjrs,
                                  womv, ws2mv, wm2s, ws2s, wpk);
  gb_main<<<NPOS_TOTAL / 16, 256, 0, stream>>>(mv, ref, s, wpk, out_mv, out_s);
}